// Round 11
// baseline (646.786 us; speedup 1.0000x reference)
//
#include <hip/hip_runtime.h>
#include <hip/hip_fp16.h>
#include <cstdint>
#include <cstddef>

#define EPS_BN 1e-5f
#define NSLICE 16          // stats accumulator shards (power of 2)

static inline int cdiv(int a, int b) { return (a + b - 1) / b; }

using half8   = __attribute__((ext_vector_type(8))) _Float16;
using floatx4 = __attribute__((ext_vector_type(4))) float;

__device__ __forceinline__ float atomAddF(float* p, float v) {
    return unsafeAtomicAdd(p, v);   // HW global_atomic_add_f32 on gfx950
}

// ================= bucketed CSR build =================
// bucket = dst >> 9 (512 nodes per bucket); NBUCK <= 256 (n <= 131072) required.
// pairs[] entries are packed: (dstLow9 << 17) | src17.

__global__ __launch_bounds__(256) void k_hist(const int* __restrict__ dst, int E,
                                              int NBLK, int NBUCK, int* __restrict__ H) {
    __shared__ int h[256];
    int t = threadIdx.x;
    h[t] = 0;
    __syncthreads();
    int base = blockIdx.x * 8192;
#pragma unroll
    for (int j = 0; j < 32; ++j) {
        int e = base + j * 256 + t;
        if (e < E) atomicAdd(&h[dst[e] >> 9], 1);
    }
    __syncthreads();
    if (t < NBUCK) H[t * NBLK + blockIdx.x] = h[t];
}

// single-block exclusive scan over m elements (m ~ 40k, L2-resident)
__global__ __launch_bounds__(256) void k_scan_one(const int* __restrict__ in, int m,
                                                  int* __restrict__ outS) {
    __shared__ int sm[256];
    int t = threadIdx.x;
    int per = (m + 255) / 256;
    int b0 = t * per;
    int b1 = b0 + per; if (b1 > m) b1 = m;
    int s = 0;
    for (int i = b0; i < b1; ++i) s += in[i];
    sm[t] = s;
    __syncthreads();
    for (int off = 1; off < 256; off <<= 1) {
        int x = (t >= off) ? sm[t - off] : 0;
        __syncthreads();
        sm[t] += x;
        __syncthreads();
    }
    int excl = sm[t] - s;
    for (int i = b0; i < b1; ++i) { int v = in[i]; outS[i] = excl; excl += v; }
}

__global__ __launch_bounds__(256) void k_bucket(const int* __restrict__ src,
                                                const int* __restrict__ dst, int E,
                                                int NBLK, int NBUCK,
                                                const int* __restrict__ S,
                                                unsigned* __restrict__ pairs) {
    __shared__ int cur[256];
    int t = threadIdx.x;
    if (t < NBUCK) cur[t] = S[t * NBLK + blockIdx.x];
    __syncthreads();
    int base = blockIdx.x * 8192;
#pragma unroll
    for (int j = 0; j < 32; ++j) {
        int e = base + j * 256 + t;
        if (e < E) {
            unsigned s = (unsigned)src[e];
            unsigned d = (unsigned)dst[e];
            int p = atomicAdd(&cur[d >> 9], 1);
            pairs[p] = ((d & 511u) << 17) | s;
        }
    }
}

__global__ __launch_bounds__(256) void k_build(const unsigned* __restrict__ pairs,
                                               const int* __restrict__ S,
                                               int NBLK, int NBUCK, int n, int E,
                                               int* __restrict__ endoff,
                                               float* __restrict__ dinv,
                                               int* __restrict__ csr) {
    int b = blockIdx.x;
    int nbase = b << 9;
    int bstart = S[b * NBLK];
    int bend = (b == NBUCK - 1) ? E : S[(b + 1) * NBLK];
    int t = threadIdx.x;
    __shared__ int sdeg[512];
    __shared__ int scur[512];
    __shared__ int stmp[256];
    sdeg[t] = 0; sdeg[t + 256] = 0;
    __syncthreads();
    for (int e = bstart + t; e < bend; e += 256)
        atomicAdd(&sdeg[pairs[e] >> 17], 1);
    __syncthreads();
    int d0 = sdeg[2 * t], d1 = sdeg[2 * t + 1];
    int ps = d0 + d1;
    stmp[t] = ps;
    __syncthreads();
    for (int off = 1; off < 256; off <<= 1) {
        int x = (t >= off) ? stmp[t - off] : 0;
        __syncthreads();
        stmp[t] += x;
        __syncthreads();
    }
    int c0 = bstart + stmp[t] - ps;
    int c1 = c0 + d0;
    scur[2 * t] = c0;
    scur[2 * t + 1] = c1;
    int v0 = nbase + 2 * t, v1 = v0 + 1;
    if (v0 < n) { endoff[v0] = c1;      dinv[v0] = rsqrtf((float)(d0 + 1)); }
    if (v1 < n) { endoff[v1] = c1 + d1; dinv[v1] = rsqrtf((float)(d1 + 1)); }
    __syncthreads();
    for (int e = bstart + t; e < bend; e += 256) {
        unsigned p = pairs[e];
        int pos = atomicAdd(&scur[p >> 17], 1);
        csr[pos] = (int)(p & 0x1FFFFu);
    }
}

// ================= prep: x->f16*dinv, weights->f16 transposed, stats zero ========
__global__ __launch_bounds__(256) void k_prep(const float* __restrict__ x,
                                              const float* __restrict__ dinv,
                                              const float* __restrict__ W1,
                                              const float* __restrict__ W2,
                                              const float* __restrict__ W3,
                                              __half* __restrict__ xh,
                                              __half* __restrict__ Wt1,
                                              __half* __restrict__ Wt2,
                                              __half* __restrict__ Wt3,
                                              float* __restrict__ stats, int n) {
    int idx = blockIdx.x * 256 + threadIdx.x;
    int nx = n * 16;
    if (idx < nx) {
        int row = idx >> 4;
        float dv = dinv[row];
        const float4* p = (const float4*)x + (size_t)idx * 2;
        float4 a = p[0], b = p[1];
        uint4 o; __half2* oh = (__half2*)&o;
        oh[0] = __floats2half2_rn(a.x * dv, a.y * dv);
        oh[1] = __floats2half2_rn(a.z * dv, a.w * dv);
        oh[2] = __floats2half2_rn(b.x * dv, b.y * dv);
        oh[3] = __floats2half2_rn(b.z * dv, b.w * dv);
        ((uint4*)xh)[idx] = o;
        return;
    }
    int r = idx - nx;
    if (r < 32768) {                         // W1: 128x256
        int k = r >> 8, c = r & 255;
        Wt1[c * 128 + k] = __float2half(W1[r]);
    } else if (r < 98304) {                  // W2: 256x256
        int r2 = r - 32768;
        int k = r2 >> 8, c = r2 & 255;
        Wt2[c * 256 + k] = __float2half(W2[r2]);
    } else if (r < 131072) {                 // W3: 256x128
        int r2 = r - 98304;
        int k = r2 >> 7, c = r2 & 127;
        Wt3[c * 256 + k] = __float2half(W3[r2]);
    } else if (r < 131072 + NSLICE * 256 * 6) {
        stats[r - 131072] = 0.f;
    }
}

// ================= CSR gather (rows pre-scaled by dinv[src]) =================
__device__ __forceinline__ void acc8(float* acc, uint4 d) {
    const __half2* h = (const __half2*)&d;
#pragma unroll
    for (int j = 0; j < 4; ++j) {
        float2 f = __half22float2(h[j]);
        acc[2 * j] += f.x; acc[2 * j + 1] += f.y;
    }
}

template<int D, bool STATS>
__global__ __launch_bounds__(256) void k_gather_h(const int* __restrict__ csr,
                                                  const int* __restrict__ endoff,
                                                  const __half* __restrict__ P,
                                                  const float* __restrict__ dinv,
                                                  __half* __restrict__ S, int n,
                                                  float* __restrict__ sums,
                                                  float* __restrict__ sqs) {
    constexpr int LPN = D / 8;
    constexpr int NPB = 256 / LPN;
    __shared__ float red[STATS ? 2048 : 1];
    int t = threadIdx.x;
    int lane = t % LPN;
    int sub = t / LPN;
    float sacc[8] = {}, sqacc[8] = {};
    for (int vb = blockIdx.x * NPB; vb < n; vb += gridDim.x * NPB) {
        int v = vb + sub;
        if (v >= n) continue;
        int beg = (v == 0) ? 0 : endoff[v - 1];
        int end = endoff[v];
        float acc[8];
        {
            uint4 d = *((const uint4*)(P + (size_t)v * D) + lane);
            const __half2* h = (const __half2*)&d;
#pragma unroll
            for (int j = 0; j < 4; ++j) {
                float2 f = __half22float2(h[j]);
                acc[2 * j] = f.x; acc[2 * j + 1] = f.y;
            }
        }
        int i = beg;
        int rem = (end - beg) & 7;
        if (rem & 4) {
            uint4 dd[4];
#pragma unroll
            for (int u = 0; u < 4; ++u)
                dd[u] = *((const uint4*)(P + (size_t)csr[i + u] * D) + lane);
#pragma unroll
            for (int u = 0; u < 4; ++u) acc8(acc, dd[u]);
            i += 4;
        }
        if (rem & 2) {
            uint4 d0 = *((const uint4*)(P + (size_t)csr[i] * D) + lane);
            uint4 d1 = *((const uint4*)(P + (size_t)csr[i + 1] * D) + lane);
            acc8(acc, d0); acc8(acc, d1);
            i += 2;
        }
        if (rem & 1) {
            uint4 d0 = *((const uint4*)(P + (size_t)csr[i] * D) + lane);
            acc8(acc, d0);
            i += 1;
        }
        if (i < end) {
            uint4 a[8];
#pragma unroll
            for (int u = 0; u < 8; ++u)
                a[u] = *((const uint4*)(P + (size_t)csr[i + u] * D) + lane);
            for (i += 8; i < end; i += 8) {
                uint4 b[8];
#pragma unroll
                for (int u = 0; u < 8; ++u)
                    b[u] = *((const uint4*)(P + (size_t)csr[i + u] * D) + lane);
#pragma unroll
                for (int u = 0; u < 8; ++u) acc8(acc, a[u]);
#pragma unroll
                for (int u = 0; u < 8; ++u) a[u] = b[u];
            }
#pragma unroll
            for (int u = 0; u < 8; ++u) acc8(acc, a[u]);
        }
        float dv = dinv[v];
        uint4 o; __half2* oh = (__half2*)&o;
#pragma unroll
        for (int j = 0; j < 4; ++j) {
            float a0 = acc[2 * j] * dv, a1 = acc[2 * j + 1] * dv;
            oh[j] = __floats2half2_rn(a0, a1);
            if (STATS) {
                sacc[2 * j] += a0;  sqacc[2 * j] += a0 * a0;
                sacc[2 * j + 1] += a1; sqacc[2 * j + 1] += a1 * a1;
            }
        }
        *((uint4*)(S + (size_t)v * D) + lane) = o;
    }
    if (STATS) {
        int slice = blockIdx.x & (NSLICE - 1);
#pragma unroll
        for (int j = 0; j < 8; ++j) red[t * 8 + j] = sacc[j];
        __syncthreads();
        if (t < D) {
            int lc = t >> 3, j = t & 7;
            float ts = 0.f;
#pragma unroll
            for (int s = 0; s < NPB; ++s) ts += red[(s * LPN + lc) * 8 + j];
            atomAddF(&sums[slice * 256 + t], ts);
        }
        __syncthreads();
#pragma unroll
        for (int j = 0; j < 8; ++j) red[t * 8 + j] = sqacc[j];
        __syncthreads();
        if (t < D) {
            int lc = t >> 3, j = t & 7;
            float tq = 0.f;
#pragma unroll
            for (int s = 0; s < NPB; ++s) tq += red[(s * LPN + lc) * 8 + j];
            atomAddF(&sqs[slice * 256 + t], tq);
        }
    }
}

// ================= MFMA GEMM: 128x128 tile, 2x2 waves of 64x64 each =============
// Register-prefetch pipeline: tile k+1's global loads issue before tile k's MFMAs.
template<int K, int NC, bool SCALE, bool BNIN, bool STATS>
__global__ __launch_bounds__(256) void k_gemm_mfma(const __half* __restrict__ A,
                                                   const __half* __restrict__ Wt,
                                                   const float* __restrict__ dinv,
                                                   const float* __restrict__ isum,
                                                   const float* __restrict__ isq,
                                                   const float* __restrict__ g,
                                                   const float* __restrict__ beta,
                                                   float* __restrict__ osum,
                                                   float* __restrict__ osq,
                                                   __half* __restrict__ C, int n) {
    constexpr int LDA = 40;
    __shared__ _Float16 As[128 * LDA];
    __shared__ _Float16 Bs[128 * LDA];
    __shared__ float ssc[BNIN ? K : 1];
    __shared__ float ssh[BNIN ? K : 1];
    __shared__ float scs[STATS ? 128 : 1];
    __shared__ float scq[STATS ? 128 : 1];
    int tid = threadIdx.x;
    if (BNIN) {
        float nf = (float)n;
        for (int i = tid; i < K; i += 256) {
            float su = 0.f, sq = 0.f;
#pragma unroll
            for (int s = 0; s < NSLICE; ++s) {
                su += isum[s * 256 + i];
                sq += isq[s * 256 + i];
            }
            float mu = su / nf;
            float var = sq / nf - mu * mu;
            float sc = g[i] * rsqrtf(var + EPS_BN);
            ssc[i] = sc; ssh[i] = beta[i] - mu * sc;
        }
        __syncthreads();
    }
    int wave = tid >> 6, lane = tid & 63;
    int wr = wave >> 1, wc = wave & 1;
    int q = lane >> 4, l16 = lane & 15;
    int row0 = blockIdx.x * 128;
    int col0 = blockIdx.y * 128;
    int sr = tid >> 2, sks = tid & 3;       // staging slot: row, k-subchunk
    const __half* Abase = A + (size_t)(row0 + sr) * K + sks * 8;
    const __half* Bbase = Wt + (size_t)(col0 + sr) * K + sks * 8;
    const __half* Abase2 = Abase + 64 * K;  // second slot (tid+256): row += 64
    const __half* Bbase2 = Bbase + 64 * K;

    floatx4 acc[4][4];
#pragma unroll
    for (int r = 0; r < 4; ++r)
#pragma unroll
        for (int c = 0; c < 4; ++c) acc[r][c] = (floatx4)0.0f;

    auto storeTiles = [&](uint4* ra, uint4* rb, int kbase) {
#pragma unroll
        for (int i = 0; i < 2; ++i) {
            uint4 d = ra[i];
            if (BNIN) {
                const __half2* h = (const __half2*)&d;
                uint4 o; __half2* oh = (__half2*)&o;
                int kb = kbase + sks * 8;
#pragma unroll
                for (int j = 0; j < 4; ++j) {
                    float2 f = __half22float2(h[j]);
                    float y0 = fmaxf(0.f, f.x * ssc[kb + 2 * j]     + ssh[kb + 2 * j]);
                    float y1 = fmaxf(0.f, f.y * ssc[kb + 2 * j + 1] + ssh[kb + 2 * j + 1]);
                    oh[j] = __floats2half2_rn(y0, y1);
                }
                d = o;
            }
            *(uint4*)&As[(sr + i * 64) * LDA + sks * 8] = d;
            *(uint4*)&Bs[(sr + i * 64) * LDA + sks * 8] = rb[i];
        }
    };

    // prologue: load + store tile 0
    uint4 ra[2], rb[2];
    ra[0] = *(const uint4*)(Abase);  ra[1] = *(const uint4*)(Abase2);
    rb[0] = *(const uint4*)(Bbase);  rb[1] = *(const uint4*)(Bbase2);
    storeTiles(ra, rb, 0);
    __syncthreads();

    for (int k0 = 32; k0 <= K; k0 += 32) {
        bool more = (k0 < K);
        if (more) {                          // issue next tile's loads early
            ra[0] = *(const uint4*)(Abase + k0);
            ra[1] = *(const uint4*)(Abase2 + k0);
            rb[0] = *(const uint4*)(Bbase + k0);
            rb[1] = *(const uint4*)(Bbase2 + k0);
        }
        half8 af[4], bf[4];
#pragma unroll
        for (int r = 0; r < 4; ++r)
            af[r] = *(const half8*)&As[(wr * 64 + r * 16 + l16) * LDA + q * 8];
#pragma unroll
        for (int c = 0; c < 4; ++c)
            bf[c] = *(const half8*)&Bs[(wc * 64 + c * 16 + l16) * LDA + q * 8];
#pragma unroll
        for (int r = 0; r < 4; ++r)
#pragma unroll
            for (int c = 0; c < 4; ++c)
                acc[r][c] = __builtin_amdgcn_mfma_f32_16x16x32_f16(af[r], bf[c], acc[r][c], 0, 0, 0);
        __syncthreads();
        if (more) {
            storeTiles(ra, rb, k0);
            __syncthreads();
        }
    }
    float colsum[4] = {};
    float colsq[4]  = {};
#pragma unroll
    for (int r = 0; r < 4; ++r) {
#pragma unroll
        for (int reg = 0; reg < 4; ++reg) {
            int grow = row0 + wr * 64 + r * 16 + q * 4 + reg;
            float sc = 1.f;
            if (SCALE) sc = (grow < n) ? dinv[grow] : 0.f;
            __half* cp = C + (size_t)grow * NC + col0 + wc * 64 + l16;
#pragma unroll
            for (int c = 0; c < 4; ++c) {
                float v = acc[r][c][reg] * sc;
                cp[c * 16] = __float2half(v);
                if (STATS && grow < n) { colsum[c] += v; colsq[c] += v * v; }
            }
        }
    }
    if (STATS) {
        if (tid < 128) { scs[tid] = 0.f; scq[tid] = 0.f; }
        __syncthreads();
#pragma unroll
        for (int c = 0; c < 4; ++c) {
            atomicAdd(&scs[wc * 64 + c * 16 + l16], colsum[c]);
            atomicAdd(&scq[wc * 64 + c * 16 + l16], colsq[c]);
        }
        __syncthreads();
        if (tid < 128) {
            int slice = blockIdx.x & (NSLICE - 1);
            atomAddF(&osum[slice * 256 + col0 + tid], scs[tid]);
            atomAddF(&osq[slice * 256 + col0 + tid], scq[tid]);
        }
    }
}

// ================= final linear, 128 rows/block, fused BN+ReLU ====================
__global__ __launch_bounds__(256) void k_out(const __half* __restrict__ H,
                                             const float* __restrict__ sums,
                                             const float* __restrict__ sqs,
                                             const float* __restrict__ g,
                                             const float* __restrict__ beta,
                                             const float* __restrict__ Wout,
                                             const float* __restrict__ bout,
                                             float* __restrict__ out, int n) {
    __shared__ float Wl[128 * 10];
    __shared__ float bl[10];
    __shared__ float osc[128];
    __shared__ float osh[128];
    __shared__ float red[256 * 10];
    int tid = threadIdx.x;
    for (int i = tid; i < 1280; i += 256) Wl[i] = Wout[i];
    if (tid < 10) bl[tid] = bout[tid];
    if (tid < 128) {
        float nf = (float)n;
        float su = 0.f, sq = 0.f;
#pragma unroll
        for (int s = 0; s < NSLICE; ++s) {
            su += sums[s * 256 + tid];
            sq += sqs[s * 256 + tid];
        }
        float mu = su / nf;
        float var = sq / nf - mu * mu;
        float sc = g[tid] * rsqrtf(var + EPS_BN);
        osc[tid] = sc; osh[tid] = beta[tid] - mu * sc;
    }
    __syncthreads();
    int rl = tid >> 1;
    int h2 = tid & 1;
    int r = blockIdx.x * 128 + rl;
    float p[10] = {};
    if (r < n) {
        const __half* a = H + (size_t)r * 128 + h2 * 64;
#pragma unroll 8
        for (int k = 0; k < 64; ++k) {
            int col = h2 * 64 + k;
            float av = fmaxf(0.f, __half2float(a[k]) * osc[col] + osh[col]);
            const float* wr = Wl + col * 10;
#pragma unroll
            for (int c = 0; c < 10; ++c) p[c] += av * wr[c];
        }
    }
    float* rr = red + (size_t)tid * 10;
#pragma unroll
    for (int c = 0; c < 10; ++c) rr[c] = p[c];
    __syncthreads();
    if (h2 == 0 && r < n) {
        const float* rb = red + (size_t)tid * 10;
#pragma unroll
        for (int c = 0; c < 10; ++c) {
            out[(size_t)r * 10 + c] = rb[c] + rb[10 + c] + bl[c];
        }
    }
}

// ================= launch =================
extern "C" void kernel_launch(void* const* d_in, const int* in_sizes, int n_in,
                              void* d_out, int out_size, void* d_ws, size_t ws_size,
                              hipStream_t stream) {
    const float* x    = (const float*)d_in[0];
    const int*   ei   = (const int*)d_in[1];
    const float* W1   = (const float*)d_in[2];
    const float* g1   = (const float*)d_in[4];
    const float* be1  = (const float*)d_in[5];
    const float* W2   = (const float*)d_in[6];
    const float* g2   = (const float*)d_in[8];
    const float* be2  = (const float*)d_in[9];
    const float* W3   = (const float*)d_in[10];
    const float* g3   = (const float*)d_in[12];
    const float* be3  = (const float*)d_in[13];
    const float* Wout = (const float*)d_in[14];
    const float* bout = (const float*)d_in[15];
    float* out = (float*)d_out;

    int n = in_sizes[0] / 128;
    int E = in_sizes[1] / 2;
    const int* esrc = ei;
    const int* edst = ei + E;
    int npad = cdiv(n, 128) * 128;
    int NBLK = cdiv(E, 8192);
    int NBUCK = (n + 511) >> 9;
    if (NBUCK > 256) return;            // guarantees n <= 131072 (src fits 17 bits)
    int m = NBUCK * NBLK;

    const size_t align = 256;
    auto al = [&](size_t s) { return (s + align - 1) & ~(align - 1); };
    size_t n4 = al((size_t)n * 4 + 512);

    const size_t statsLayer = (size_t)NSLICE * 256 * 2 * 4;
    const size_t statsTotal = statsLayer * 3;

    char* ws = (char*)d_ws;
    size_t o_end   = 0;
    size_t o_dinv  = o_end + n4;
    size_t o_stats = o_dinv + n4;
    size_t o_H     = o_stats + statsTotal;
    size_t o_Hs    = o_H + al((size_t)m * 4);
    size_t o_csr   = o_Hs + al((size_t)m * 4);
    size_t o_pairs = o_csr + al((size_t)E * 4);
    size_t o_w1    = o_pairs + al((size_t)E * 4);
    size_t o_w2    = o_w1 + al(256 * 128 * 2);
    size_t o_w3    = o_w2 + al(256 * 256 * 2);
    size_t o_A128a = o_w3 + al(128 * 256 * 2);
    size_t o_A128b = o_A128a + al((size_t)npad * 128 * 2);
    size_t o_A256a = o_A128b + al((size_t)npad * 128 * 2);
    size_t o_A256b = o_A256a + al((size_t)npad * 256 * 2);
    size_t need    = o_A256b + (size_t)npad * 256 * 2;
    if (ws_size < need) return;

    int*      endoff = (int*)(ws + o_end);
    float*    dinv   = (float*)(ws + o_dinv);
    float*    stats  = (float*)(ws + o_stats);
    float*    sums1  = stats;
    float*    sqs1   = sums1 + NSLICE * 256;
    float*    sums2  = (float*)(ws + o_stats + statsLayer);
    float*    sqs2   = sums2 + NSLICE * 256;
    float*    sums3  = (float*)(ws + o_stats + 2 * statsLayer);
    float*    sqs3   = sums3 + NSLICE * 256;
    int*      H      = (int*)(ws + o_H);
    int*      Hs     = (int*)(ws + o_Hs);
    int*      csr    = (int*)(ws + o_csr);
    unsigned* pairs  = (unsigned*)(ws + o_pairs);
    __half*   Wt1    = (__half*)(ws + o_w1);
    __half*   Wt2    = (__half*)(ws + o_w2);
    __half*   Wt3    = (__half*)(ws + o_w3);
    __half*   xh     = (__half*)(ws + o_A128a);
    __half*   S3     = (__half*)(ws + o_A128a);
    __half*   G1     = (__half*)(ws + o_A128b);
    __half*   P3     = (__half*)(ws + o_A128b);
    __half*   P1     = (__half*)(ws + o_A256a);
    __half*   S2     = (__half*)(ws + o_A256a);
    __half*   P2     = (__half*)(ws + o_A256b);

    // ---- bucketed CSR build (hist -> 1-block scan -> bucket -> build) ----
    k_hist<<<NBLK, 256, 0, stream>>>(edst, E, NBLK, NBUCK, H);
    k_scan_one<<<1, 256, 0, stream>>>(H, m, Hs);
    k_bucket<<<NBLK, 256, 0, stream>>>(esrc, edst, E, NBLK, NBUCK, Hs, pairs);
    k_build<<<NBUCK, 256, 0, stream>>>(pairs, Hs, NBLK, NBUCK, n, E, endoff, dinv, csr);

    // ---- prep: x2h + weight transpose + stats zero ----
    int prepTotal = n * 16 + 131072 + NSLICE * 256 * 6;
    k_prep<<<cdiv(prepTotal, 256), 256, 0, stream>>>(
        x, dinv, W1, W2, W3, xh, Wt1, Wt2, Wt3, stats, n);

    // ---- layer 1: G1 = gather(xh); P1 = G1@W1 (+stats1) ----
    k_gather_h<128, false><<<cdiv(n, 16), 256, 0, stream>>>(
        csr, endoff, xh, dinv, G1, n, nullptr, nullptr);
    k_gemm_mfma<128, 256, false, false, true><<<dim3(npad / 128, 2), 256, 0, stream>>>(
        G1, Wt1, dinv, nullptr, nullptr, nullptr, nullptr, sums1, sqs1, P1, n);

    // ---- layer 2: P2 = (BN1(P1)@W2)*dinv; S2 = gather(P2) (+stats2) ----
    k_gemm_mfma<256, 256, true, true, false><<<dim3(npad / 128, 2), 256, 0, stream>>>(
        P1, Wt2, dinv, sums1, sqs1, g1, be1, nullptr, nullptr, P2, n);
    k_gather_h<256, true><<<cdiv(n, 8), 256, 0, stream>>>(
        csr, endoff, P2, dinv, S2, n, sums2, sqs2);

    // ---- layer 3: P3 = (BN2(S2)@W3)*dinv; S3 = gather(P3) (+stats3) ----
    k_gemm_mfma<256, 128, true, true, false><<<dim3(npad / 128, 1), 256, 0, stream>>>(
        S2, Wt3, dinv, sums2, sqs2, g2, be2, nullptr, nullptr, P3, n);
    k_gather_h<128, true><<<cdiv(n, 16), 256, 0, stream>>>(
        csr, endoff, P3, dinv, S3, n, sums3, sqs3);

    // ---- output: out = ReLU(BN3(S3)) @ Wout + bout ----
    k_out<<<cdiv(n, 128), 256, 0, stream>>>(S3, sums3, sqs3, g3, be3, Wout, bout, out, n);
}

// Round 12
// 567.809 us; speedup vs baseline: 1.1391x; 1.1391x over previous
//
#include <hip/hip_runtime.h>
#include <hip/hip_fp16.h>
#include <cstdint>
#include <cstddef>

#define EPS_BN 1e-5f
#define NSLICE 16          // stats accumulator shards (power of 2)

static inline int cdiv(int a, int b) { return (a + b - 1) / b; }

using half8   = __attribute__((ext_vector_type(8))) _Float16;
using floatx4 = __attribute__((ext_vector_type(4))) float;

__device__ __forceinline__ float atomAddF(float* p, float v) {
    return unsafeAtomicAdd(p, v);   // HW global_atomic_add_f32 on gfx950
}

// ================= bucketed CSR build =================
// bucket = dst >> 9 (512 nodes per bucket); NBUCK <= 256 (n <= 131072) required.
// pairs[] entries are packed: (dstLow9 << 17) | src17.

__global__ __launch_bounds__(256) void k_hist(const int* __restrict__ dst, int E,
                                              int NBLK, int NBUCK, int* __restrict__ H) {
    __shared__ int h[256];
    int t = threadIdx.x;
    h[t] = 0;
    __syncthreads();
    int base = blockIdx.x * 4096;
#pragma unroll
    for (int j = 0; j < 16; ++j) {
        int e = base + j * 256 + t;
        if (e < E) atomicAdd(&h[dst[e] >> 9], 1);
    }
    __syncthreads();
    if (t < NBUCK) H[t * NBLK + blockIdx.x] = h[t];
}

__global__ __launch_bounds__(256) void k_scan_reduce(const int* __restrict__ in, int m,
                                                     int* __restrict__ bsum) {
    int base = blockIdx.x * 1024;
    int t = threadIdx.x;
    int s = 0;
#pragma unroll
    for (int i = 0; i < 4; ++i) {
        int idx = base + t * 4 + i;
        if (idx < m) s += in[idx];
    }
    __shared__ int sm[256];
    sm[t] = s;
    __syncthreads();
    for (int off = 128; off > 0; off >>= 1) {
        if (t < off) sm[t] += sm[t + off];
        __syncthreads();
    }
    if (t == 0) bsum[blockIdx.x] = sm[0];
}

__global__ void k_scan_bsum(int* __restrict__ bsum, int nb) {
    if (threadIdx.x == 0 && blockIdx.x == 0) {
        int acc = 0;
        for (int i = 0; i < nb; ++i) { int v = bsum[i]; bsum[i] = acc; acc += v; }
    }
}

__global__ __launch_bounds__(256) void k_scan_final(const int* __restrict__ in, int m,
                                                    const int* __restrict__ bsum,
                                                    int* __restrict__ outS) {
    int base = blockIdx.x * 1024;
    int t = threadIdx.x;
    int v[4];
    int s = 0;
#pragma unroll
    for (int i = 0; i < 4; ++i) {
        int idx = base + t * 4 + i;
        v[i] = (idx < m) ? in[idx] : 0;
        s += v[i];
    }
    __shared__ int sm[256];
    sm[t] = s;
    __syncthreads();
    for (int off = 1; off < 256; off <<= 1) {
        int x = (t >= off) ? sm[t - off] : 0;
        __syncthreads();
        sm[t] += x;
        __syncthreads();
    }
    int excl = sm[t] - s + bsum[blockIdx.x];
#pragma unroll
    for (int i = 0; i < 4; ++i) {
        int idx = base + t * 4 + i;
        if (idx < m) { outS[idx] = excl; excl += v[i]; }
    }
}

__global__ __launch_bounds__(256) void k_bucket(const int* __restrict__ src,
                                                const int* __restrict__ dst, int E,
                                                int NBLK, int NBUCK,
                                                const int* __restrict__ S,
                                                unsigned* __restrict__ pairs) {
    __shared__ int cur[256];
    int t = threadIdx.x;
    if (t < NBUCK) cur[t] = S[t * NBLK + blockIdx.x];
    __syncthreads();
    int base = blockIdx.x * 4096;
#pragma unroll
    for (int j = 0; j < 16; ++j) {
        int e = base + j * 256 + t;
        if (e < E) {
            unsigned s = (unsigned)src[e];
            unsigned d = (unsigned)dst[e];
            int p = atomicAdd(&cur[d >> 9], 1);
            pairs[p] = ((d & 511u) << 17) | s;
        }
    }
}

__global__ __launch_bounds__(256) void k_build(const unsigned* __restrict__ pairs,
                                               const int* __restrict__ S,
                                               int NBLK, int NBUCK, int n, int E,
                                               int* __restrict__ endoff,
                                               float* __restrict__ dinv,
                                               int* __restrict__ csr) {
    int b = blockIdx.x;
    int nbase = b << 9;
    int bstart = S[b * NBLK];
    int bend = (b == NBUCK - 1) ? E : S[(b + 1) * NBLK];
    int t = threadIdx.x;
    __shared__ int sdeg[512];
    __shared__ int scur[512];
    __shared__ int stmp[256];
    sdeg[t] = 0; sdeg[t + 256] = 0;
    __syncthreads();
    for (int e = bstart + t; e < bend; e += 256)
        atomicAdd(&sdeg[pairs[e] >> 17], 1);
    __syncthreads();
    int d0 = sdeg[2 * t], d1 = sdeg[2 * t + 1];
    int ps = d0 + d1;
    stmp[t] = ps;
    __syncthreads();
    for (int off = 1; off < 256; off <<= 1) {
        int x = (t >= off) ? stmp[t - off] : 0;
        __syncthreads();
        stmp[t] += x;
        __syncthreads();
    }
    int c0 = bstart + stmp[t] - ps;
    int c1 = c0 + d0;
    scur[2 * t] = c0;
    scur[2 * t + 1] = c1;
    int v0 = nbase + 2 * t, v1 = v0 + 1;
    if (v0 < n) { endoff[v0] = c1;      dinv[v0] = rsqrtf((float)(d0 + 1)); }
    if (v1 < n) { endoff[v1] = c1 + d1; dinv[v1] = rsqrtf((float)(d1 + 1)); }
    __syncthreads();
    for (int e = bstart + t; e < bend; e += 256) {
        unsigned p = pairs[e];
        int pos = atomicAdd(&scur[p >> 17], 1);
        csr[pos] = (int)(p & 0x1FFFFu);
    }
}

// ================= prep: x->f16*dinv, weights->f16 transposed, stats zero ========
__global__ __launch_bounds__(256) void k_prep(const float* __restrict__ x,
                                              const float* __restrict__ dinv,
                                              const float* __restrict__ W1,
                                              const float* __restrict__ W2,
                                              const float* __restrict__ W3,
                                              __half* __restrict__ xh,
                                              __half* __restrict__ Wt1,
                                              __half* __restrict__ Wt2,
                                              __half* __restrict__ Wt3,
                                              float* __restrict__ stats, int n) {
    int idx = blockIdx.x * 256 + threadIdx.x;
    int nx = n * 16;
    if (idx < nx) {                          // x -> f16, pre-scaled by dinv (8-half chunks)
        int row = idx >> 4;
        float dv = dinv[row];
        const float4* p = (const float4*)x + (size_t)idx * 2;
        float4 a = p[0], b = p[1];
        uint4 o; __half2* oh = (__half2*)&o;
        oh[0] = __floats2half2_rn(a.x * dv, a.y * dv);
        oh[1] = __floats2half2_rn(a.z * dv, a.w * dv);
        oh[2] = __floats2half2_rn(b.x * dv, b.y * dv);
        oh[3] = __floats2half2_rn(b.z * dv, b.w * dv);
        ((uint4*)xh)[idx] = o;
        return;
    }
    int r = idx - nx;
    if (r < 32768) {                         // W1: 128x256
        int k = r >> 8, c = r & 255;
        Wt1[c * 128 + k] = __float2half(W1[r]);
    } else if (r < 98304) {                  // W2: 256x256
        int r2 = r - 32768;
        int k = r2 >> 8, c = r2 & 255;
        Wt2[c * 256 + k] = __float2half(W2[r2]);
    } else if (r < 131072) {                 // W3: 256x128
        int r2 = r - 98304;
        int k = r2 >> 7, c = r2 & 127;
        Wt3[c * 256 + k] = __float2half(W3[r2]);
    } else if (r < 131072 + NSLICE * 256 * 6) {
        stats[r - 131072] = 0.f;             // zero all 3 layers' sliced sums/sqs
    }
}

// ================= CSR gather (rows pre-scaled by dinv[src]) =================
__device__ __forceinline__ void acc8(float* acc, uint4 d) {
    const __half2* h = (const __half2*)&d;
#pragma unroll
    for (int j = 0; j < 4; ++j) {
        float2 f = __half22float2(h[j]);
        acc[2 * j] += f.x; acc[2 * j + 1] += f.y;
    }
}

template<int D, bool STATS>
__global__ __launch_bounds__(256) void k_gather_h(const int* __restrict__ csr,
                                                  const int* __restrict__ endoff,
                                                  const __half* __restrict__ P,
                                                  const float* __restrict__ dinv,
                                                  __half* __restrict__ S, int n,
                                                  float* __restrict__ sums,
                                                  float* __restrict__ sqs) {
    constexpr int LPN = D / 8;
    constexpr int NPB = 256 / LPN;
    __shared__ float red[STATS ? 2048 : 1];
    int t = threadIdx.x;
    int lane = t % LPN;
    int sub = t / LPN;
    float sacc[8] = {}, sqacc[8] = {};
    for (int vb = blockIdx.x * NPB; vb < n; vb += gridDim.x * NPB) {
        int v = vb + sub;
        if (v >= n) continue;
        int beg = (v == 0) ? 0 : endoff[v - 1];
        int end = endoff[v];
        float acc[8];
        {
            uint4 d = *((const uint4*)(P + (size_t)v * D) + lane);   // self term
            const __half2* h = (const __half2*)&d;
#pragma unroll
            for (int j = 0; j < 4; ++j) {
                float2 f = __half22float2(h[j]);
                acc[2 * j] = f.x; acc[2 * j + 1] = f.y;
            }
        }
        int i = beg;
        int rem = (end - beg) & 7;
        if (rem & 4) {
            uint4 dd[4];
#pragma unroll
            for (int u = 0; u < 4; ++u)
                dd[u] = *((const uint4*)(P + (size_t)csr[i + u] * D) + lane);
#pragma unroll
            for (int u = 0; u < 4; ++u) acc8(acc, dd[u]);
            i += 4;
        }
        if (rem & 2) {
            uint4 d0 = *((const uint4*)(P + (size_t)csr[i] * D) + lane);
            uint4 d1 = *((const uint4*)(P + (size_t)csr[i + 1] * D) + lane);
            acc8(acc, d0); acc8(acc, d1);
            i += 2;
        }
        if (rem & 1) {
            uint4 d0 = *((const uint4*)(P + (size_t)csr[i] * D) + lane);
            acc8(acc, d0);
            i += 1;
        }
        if (i < end) {                       // multiple of 8 remaining
            uint4 a[8];
#pragma unroll
            for (int u = 0; u < 8; ++u)
                a[u] = *((const uint4*)(P + (size_t)csr[i + u] * D) + lane);
            for (i += 8; i < end; i += 8) {
                uint4 b[8];
#pragma unroll
                for (int u = 0; u < 8; ++u)
                    b[u] = *((const uint4*)(P + (size_t)csr[i + u] * D) + lane);
#pragma unroll
                for (int u = 0; u < 8; ++u) acc8(acc, a[u]);
#pragma unroll
                for (int u = 0; u < 8; ++u) a[u] = b[u];
            }
#pragma unroll
            for (int u = 0; u < 8; ++u) acc8(acc, a[u]);
        }
        float dv = dinv[v];
        uint4 o; __half2* oh = (__half2*)&o;
#pragma unroll
        for (int j = 0; j < 4; ++j) {
            float a0 = acc[2 * j] * dv, a1 = acc[2 * j + 1] * dv;
            oh[j] = __floats2half2_rn(a0, a1);
            if (STATS) {
                sacc[2 * j] += a0;  sqacc[2 * j] += a0 * a0;
                sacc[2 * j + 1] += a1; sqacc[2 * j + 1] += a1 * a1;
            }
        }
        *((uint4*)(S + (size_t)v * D) + lane) = o;
    }
    if (STATS) {
        int slice = blockIdx.x & (NSLICE - 1);
#pragma unroll
        for (int j = 0; j < 8; ++j) red[t * 8 + j] = sacc[j];
        __syncthreads();
        if (t < D) {
            int lc = t >> 3, j = t & 7;
            float ts = 0.f;
#pragma unroll
            for (int s = 0; s < NPB; ++s) ts += red[(s * LPN + lc) * 8 + j];
            atomAddF(&sums[slice * 256 + t], ts);
        }
        __syncthreads();
#pragma unroll
        for (int j = 0; j < 8; ++j) red[t * 8 + j] = sqacc[j];
        __syncthreads();
        if (t < D) {
            int lc = t >> 3, j = t & 7;
            float tq = 0.f;
#pragma unroll
            for (int s = 0; s < NPB; ++s) tq += red[(s * LPN + lc) * 8 + j];
            atomAddF(&sqs[slice * 256 + t], tq);
        }
    }
}

// ================= MFMA GEMM: 128x128 tile, 2x2 waves of 64x64 each =============
// Per wave per K-32 step: 4 A-frag + 4 B-frag ds_read_b128, 16 MFMA.
template<int K, int NC, bool SCALE, bool BNIN, bool STATS>
__global__ __launch_bounds__(256) void k_gemm_mfma(const __half* __restrict__ A,
                                                   const __half* __restrict__ Wt,
                                                   const float* __restrict__ dinv,
                                                   const float* __restrict__ isum,
                                                   const float* __restrict__ isq,
                                                   const float* __restrict__ g,
                                                   const float* __restrict__ beta,
                                                   float* __restrict__ osum,
                                                   float* __restrict__ osq,
                                                   __half* __restrict__ C, int n) {
    constexpr int LDA = 40;
    __shared__ _Float16 As[128 * LDA];
    __shared__ _Float16 Bs[128 * LDA];
    __shared__ float ssc[BNIN ? K : 1];
    __shared__ float ssh[BNIN ? K : 1];
    __shared__ float scs[STATS ? 128 : 1];
    __shared__ float scq[STATS ? 128 : 1];
    int tid = threadIdx.x;
    if (BNIN) {
        float nf = (float)n;
        for (int i = tid; i < K; i += 256) {
            float su = 0.f, sq = 0.f;
#pragma unroll
            for (int s = 0; s < NSLICE; ++s) {
                su += isum[s * 256 + i];
                sq += isq[s * 256 + i];
            }
            float mu = su / nf;
            float var = sq / nf - mu * mu;
            float sc = g[i] * rsqrtf(var + EPS_BN);
            ssc[i] = sc; ssh[i] = beta[i] - mu * sc;
        }
        __syncthreads();
    }
    int wave = tid >> 6, lane = tid & 63;
    int wr = wave >> 1, wc = wave & 1;        // 2x2 wave grid, 64x64 per wave
    int q = lane >> 4, l16 = lane & 15;
    int row0 = blockIdx.x * 128;
    int col0 = blockIdx.y * 128;
    floatx4 acc[4][4];
#pragma unroll
    for (int r = 0; r < 4; ++r)
#pragma unroll
        for (int c = 0; c < 4; ++c) acc[r][c] = (floatx4)0.0f;

    for (int k0 = 0; k0 < K; k0 += 32) {
#pragma unroll
        for (int i = 0; i < 2; ++i) {       // A tile 128 x 32
            int s = tid + i * 256;
            int r = s >> 2, ks = s & 3;
            uint4 d = *(const uint4*)(A + (size_t)(row0 + r) * K + k0 + ks * 8);
            if (BNIN) {
                const __half2* h = (const __half2*)&d;
                uint4 o; __half2* oh = (__half2*)&o;
                int kb = k0 + ks * 8;
#pragma unroll
                for (int j = 0; j < 4; ++j) {
                    float2 f = __half22float2(h[j]);
                    float y0 = fmaxf(0.f, f.x * ssc[kb + 2 * j]     + ssh[kb + 2 * j]);
                    float y1 = fmaxf(0.f, f.y * ssc[kb + 2 * j + 1] + ssh[kb + 2 * j + 1]);
                    oh[j] = __floats2half2_rn(y0, y1);
                }
                d = o;
            }
            *(uint4*)&As[r * LDA + ks * 8] = d;
        }
#pragma unroll
        for (int i = 0; i < 2; ++i) {       // B tile 128 x 32
            int s = tid + i * 256;
            int r = s >> 2, ks = s & 3;
            uint4 d = *(const uint4*)(Wt + (size_t)(col0 + r) * K + k0 + ks * 8);
            *(uint4*)&Bs[r * LDA + ks * 8] = d;
        }
        __syncthreads();
        half8 af[4], bf[4];
#pragma unroll
        for (int r = 0; r < 4; ++r)
            af[r] = *(const half8*)&As[(wr * 64 + r * 16 + l16) * LDA + q * 8];
#pragma unroll
        for (int c = 0; c < 4; ++c)
            bf[c] = *(const half8*)&Bs[(wc * 64 + c * 16 + l16) * LDA + q * 8];
#pragma unroll
        for (int r = 0; r < 4; ++r)
#pragma unroll
            for (int c = 0; c < 4; ++c)
                acc[r][c] = __builtin_amdgcn_mfma_f32_16x16x32_f16(af[r], bf[c], acc[r][c], 0, 0, 0);
        __syncthreads();
    }
    float colsum[4] = {};
    float colsq[4]  = {};
#pragma unroll
    for (int r = 0; r < 4; ++r) {
#pragma unroll
        for (int reg = 0; reg < 4; ++reg) {
            int grow = row0 + wr * 64 + r * 16 + q * 4 + reg;
            float sc = 1.f;
            if (SCALE) sc = (grow < n) ? dinv[grow] : 0.f;
            __half* cp = C + (size_t)grow * NC + col0 + wc * 64 + l16;
#pragma unroll
            for (int c = 0; c < 4; ++c) {
                float v = acc[r][c][reg] * sc;
                cp[c * 16] = __float2half(v);
                if (STATS && grow < n) { colsum[c] += v; colsq[c] += v * v; }
            }
        }
    }
    if (STATS) {
        if (tid < 128) { scs[tid] = 0.f; scq[tid] = 0.f; }
        __syncthreads();
#pragma unroll
        for (int c = 0; c < 4; ++c) {
            atomicAdd(&scs[wc * 64 + c * 16 + l16], colsum[c]);
            atomicAdd(&scq[wc * 64 + c * 16 + l16], colsq[c]);
        }
        __syncthreads();
        if (tid < 128) {
            int slice = blockIdx.x & (NSLICE - 1);
            atomAddF(&osum[slice * 256 + col0 + tid], scs[tid]);
            atomAddF(&osq[slice * 256 + col0 + tid], scq[tid]);
        }
    }
}

// ================= final linear, 128 rows/block, fused BN+ReLU ====================
__global__ __launch_bounds__(256) void k_out(const __half* __restrict__ H,
                                             const float* __restrict__ sums,
                                             const float* __restrict__ sqs,
                                             const float* __restrict__ g,
                                             const float* __restrict__ beta,
                                             const float* __restrict__ Wout,
                                             const float* __restrict__ bout,
                                             float* __restrict__ out, int n) {
    __shared__ float Wl[128 * 10];
    __shared__ float bl[10];
    __shared__ float osc[128];
    __shared__ float osh[128];
    __shared__ float red[256 * 10];
    int tid = threadIdx.x;
    for (int i = tid; i < 1280; i += 256) Wl[i] = Wout[i];
    if (tid < 10) bl[tid] = bout[tid];
    if (tid < 128) {
        float nf = (float)n;
        float su = 0.f, sq = 0.f;
#pragma unroll
        for (int s = 0; s < NSLICE; ++s) {
            su += sums[s * 256 + tid];
            sq += sqs[s * 256 + tid];
        }
        float mu = su / nf;
        float var = sq / nf - mu * mu;
        float sc = g[tid] * rsqrtf(var + EPS_BN);
        osc[tid] = sc; osh[tid] = beta[tid] - mu * sc;
    }
    __syncthreads();
    int rl = tid >> 1;          // 0..127
    int h2 = tid & 1;           // which 64-col half
    int r = blockIdx.x * 128 + rl;
    float p[10] = {};
    if (r < n) {
        const __half* a = H + (size_t)r * 128 + h2 * 64;
#pragma unroll 8
        for (int k = 0; k < 64; ++k) {
            int col = h2 * 64 + k;
            float av = fmaxf(0.f, __half2float(a[k]) * osc[col] + osh[col]);
            const float* wr = Wl + col * 10;
#pragma unroll
            for (int c = 0; c < 10; ++c) p[c] += av * wr[c];
        }
    }
    float* rr = red + (size_t)tid * 10;
#pragma unroll
    for (int c = 0; c < 10; ++c) rr[c] = p[c];
    __syncthreads();
    if (h2 == 0 && r < n) {
        const float* rb = red + (size_t)tid * 10;
#pragma unroll
        for (int c = 0; c < 10; ++c) {
            out[(size_t)r * 10 + c] = rb[c] + rb[10 + c] + bl[c];
        }
    }
}

// ================= launch =================
extern "C" void kernel_launch(void* const* d_in, const int* in_sizes, int n_in,
                              void* d_out, int out_size, void* d_ws, size_t ws_size,
                              hipStream_t stream) {
    const float* x    = (const float*)d_in[0];
    const int*   ei   = (const int*)d_in[1];
    const float* W1   = (const float*)d_in[2];
    const float* g1   = (const float*)d_in[4];
    const float* be1  = (const float*)d_in[5];
    const float* W2   = (const float*)d_in[6];
    const float* g2   = (const float*)d_in[8];
    const float* be2  = (const float*)d_in[9];
    const float* W3   = (const float*)d_in[10];
    const float* g3   = (const float*)d_in[12];
    const float* be3  = (const float*)d_in[13];
    const float* Wout = (const float*)d_in[14];
    const float* bout = (const float*)d_in[15];
    float* out = (float*)d_out;

    int n = in_sizes[0] / 128;
    int E = in_sizes[1] / 2;
    const int* esrc = ei;
    const int* edst = ei + E;
    int npad = cdiv(n, 128) * 128;
    int NBLK = cdiv(E, 4096);
    int NBUCK = (n + 511) >> 9;
    if (NBUCK > 256) return;            // guarantees n <= 131072 (src fits 17 bits)
    int m = NBUCK * NBLK;
    int nb2 = cdiv(m, 1024);

    const size_t align = 256;
    auto al = [&](size_t s) { return (s + align - 1) & ~(align - 1); };
    size_t n4 = al((size_t)n * 4 + 512);

    const size_t statsLayer = (size_t)NSLICE * 256 * 2 * 4;
    const size_t statsTotal = statsLayer * 3;

    char* ws = (char*)d_ws;
    size_t o_end   = 0;
    size_t o_dinv  = o_end + n4;
    size_t o_stats = o_dinv + n4;
    size_t o_bsum  = o_stats + statsTotal;
    size_t o_H     = o_bsum + 1024;
    size_t o_Hs    = o_H + al((size_t)m * 4);
    size_t o_csr   = o_Hs + al((size_t)m * 4);
    size_t o_pairs = o_csr + al((size_t)E * 4);
    size_t o_w1    = o_pairs + al((size_t)E * 4);
    size_t o_w2    = o_w1 + al(256 * 128 * 2);
    size_t o_w3    = o_w2 + al(256 * 256 * 2);
    size_t o_A128a = o_w3 + al(128 * 256 * 2);
    size_t o_A128b = o_A128a + al((size_t)npad * 128 * 2);
    size_t o_A256a = o_A128b + al((size_t)npad * 128 * 2);
    size_t o_A256b = o_A256a + al((size_t)npad * 256 * 2);
    size_t need    = o_A256b + (size_t)npad * 256 * 2;
    if (ws_size < need) return;

    int*      endoff = (int*)(ws + o_end);
    float*    dinv   = (float*)(ws + o_dinv);
    float*    stats  = (float*)(ws + o_stats);
    float*    sums1  = stats;
    float*    sqs1   = sums1 + NSLICE * 256;
    float*    sums2  = (float*)(ws + o_stats + statsLayer);
    float*    sqs2   = sums2 + NSLICE * 256;
    float*    sums3  = (float*)(ws + o_stats + 2 * statsLayer);
    float*    sqs3   = sums3 + NSLICE * 256;
    int*      bsum   = (int*)(ws + o_bsum);
    int*      H      = (int*)(ws + o_H);
    int*      Hs     = (int*)(ws + o_Hs);
    int*      csr    = (int*)(ws + o_csr);
    unsigned* pairs  = (unsigned*)(ws + o_pairs);
    __half*   Wt1    = (__half*)(ws + o_w1);
    __half*   Wt2    = (__half*)(ws + o_w2);
    __half*   Wt3    = (__half*)(ws + o_w3);
    __half*   xh     = (__half*)(ws + o_A128a);
    __half*   S3     = (__half*)(ws + o_A128a);
    __half*   G1     = (__half*)(ws + o_A128b);
    __half*   P3     = (__half*)(ws + o_A128b);
    __half*   P1     = (__half*)(ws + o_A256a);
    __half*   S2     = (__half*)(ws + o_A256a);
    __half*   P2     = (__half*)(ws + o_A256b);

    // ---- bucketed CSR build ----
    k_hist<<<NBLK, 256, 0, stream>>>(edst, E, NBLK, NBUCK, H);
    k_scan_reduce<<<nb2, 256, 0, stream>>>(H, m, bsum);
    k_scan_bsum<<<1, 64, 0, stream>>>(bsum, nb2);
    k_scan_final<<<nb2, 256, 0, stream>>>(H, m, bsum, Hs);
    k_bucket<<<NBLK, 256, 0, stream>>>(esrc, edst, E, NBLK, NBUCK, Hs, pairs);
    k_build<<<NBUCK, 256, 0, stream>>>(pairs, Hs, NBLK, NBUCK, n, E, endoff, dinv, csr);

    // ---- prep: x2h + weight transpose + stats zero (one kernel) ----
    int prepTotal = n * 16 + 131072 + NSLICE * 256 * 6;
    k_prep<<<cdiv(prepTotal, 256), 256, 0, stream>>>(
        x, dinv, W1, W2, W3, xh, Wt1, Wt2, Wt3, stats, n);

    // ---- layer 1: G1 = gather(xh); P1 = G1@W1 (+stats1) ----
    k_gather_h<128, false><<<cdiv(n, 16), 256, 0, stream>>>(
        csr, endoff, xh, dinv, G1, n, nullptr, nullptr);
    k_gemm_mfma<128, 256, false, false, true><<<dim3(npad / 128, 2), 256, 0, stream>>>(
        G1, Wt1, dinv, nullptr, nullptr, nullptr, nullptr, sums1, sqs1, P1, n);

    // ---- layer 2: P2 = (BN1(P1)@W2)*dinv; S2 = gather(P2) (+stats2) ----
    k_gemm_mfma<256, 256, true, true, false><<<dim3(npad / 128, 2), 256, 0, stream>>>(
        P1, Wt2, dinv, sums1, sqs1, g1, be1, nullptr, nullptr, P2, n);
    k_gather_h<256, true><<<cdiv(n, 8), 256, 0, stream>>>(
        csr, endoff, P2, dinv, S2, n, sums2, sqs2);

    // ---- layer 3: P3 = (BN2(S2)@W3)*dinv; S3 = gather(P3) (+stats3) ----
    k_gemm_mfma<256, 128, true, true, false><<<dim3(npad / 128, 1), 256, 0, stream>>>(
        S2, Wt3, dinv, sums2, sqs2, g2, be2, nullptr, nullptr, P3, n);
    k_gather_h<128, true><<<cdiv(n, 16), 256, 0, stream>>>(
        csr, endoff, P3, dinv, S3, n, sums3, sqs3);

    // ---- output: out = ReLU(BN3(S3)) @ Wout + bout ----
    k_out<<<cdiv(n, 128), 256, 0, stream>>>(S3, sums3, sqs3, g3, be3, Wout, bout, out, n);
}